// Round 1
// baseline (717.426 us; speedup 1.0000x reference)
//
#include <hip/hip_runtime.h>

// NeRF renderer pipeline for MI355X (gfx950).
// Stages: pack weights->bf16 MFMA frags | ray setup | density MLP (coarse) |
// importance resample | density MLP (fine) | merge+composite weights |
// color MLP | per-ray image/depth/distortion-loss.
// MLP hidden layers use v_mfma_f32_16x16x32_bf16; fp32 accumulate.

typedef float f32x4 __attribute__((ext_vector_type(4)));
typedef __bf16 bf16x8 __attribute__((ext_vector_type(8)));
typedef unsigned short u16x8 __attribute__((ext_vector_type(8)));

#define NRAYS 2048
#define NSTEP 128
#define TSAMP 256
#define MIN_NEAR 0.05f

__device__ __forceinline__ unsigned short f2bf(float f) {
  unsigned int u = __float_as_uint(f);
  u += 0x7FFFu + ((u >> 16) & 1u);   // round-to-nearest-even
  return (unsigned short)(u >> 16);
}

// ---------------------------------------------------------------- weight pack
// dst[((kt*NT+nt)*64+lane)*8+j] = W[k][n], k=kt*32+(lane>>4)*8+j, n=nt*16+(lane&15)
// (B-fragment layout of mfma_f32_16x16x32_bf16: n=lane&15, k=quad*8+j)
__global__ void k_pack(const float* __restrict__ W, unsigned short* __restrict__ dst,
                       int K, int Norig, int NT, int total) {
  int idx = blockIdx.x * 256 + threadIdx.x;
  if (idx >= total) return;
  int per = NT * 512;
  int kt = idx / per;
  int rm = idx % per;
  int nt = rm >> 9;
  int lane = (rm >> 3) & 63;
  int j = rm & 7;
  int k = kt * 32 + ((lane >> 4) << 3) + j;
  int n = nt * 16 + (lane & 15);
  float v = (k < K && n < Norig) ? W[k * Norig + n] : 0.0f;
  dst[idx] = f2bf(v);
}

// ---------------------------------------------------------------- ray setup
__global__ void k_raysetup(const float* __restrict__ o, const float* __restrict__ d,
                           float* __restrict__ z_c) {
  int r = blockIdx.x, i = threadIdx.x;  // 128 threads
  float ox = o[r * 3], oy = o[r * 3 + 1], oz = o[r * 3 + 2];
  float dx = d[r * 3], dy = d[r * 3 + 1], dz = d[r * 3 + 2];
  float b = ox * dx + oy * dy + oz * dz;
  float c = ox * ox + oy * oy + oz * oz - 1.0f;
  float disc = fmaxf(b * b - c, 0.0f);
  float zmax = fmaxf(-b + sqrtf(disc), MIN_NEAR + 1e-3f);
  float zmin = MIN_NEAR;
  float t = (float)i / 127.0f;
  float z = zmin + (zmax - zmin) * t;
  z = fminf(fmaxf(z, zmin), zmax);
  z_c[r * NSTEP + i] = z;
}

// ---------------------------------------------------------------- MFMA helpers
// LDS h layout: h[p][n] at u16 offset p*256 + ((n>>3)^(p&31))*8 + (n&7) (XOR swizzle)
__device__ __forceinline__ void epilogue_relu_store(unsigned short* hout, const f32x4* acc,
                                                    const float* __restrict__ bias,
                                                    int m0, int lane) {
  int quad = lane >> 4, ncol = lane & 15;
#pragma unroll
  for (int nt = 0; nt < 16; ++nt) {
    int n = nt * 16 + ncol;
    float bv = bias[n];
#pragma unroll
    for (int rr = 0; rr < 4; ++rr) {
      int prow = m0 + quad * 4 + rr;
      float v = fmaxf(acc[nt][rr] + bv, 0.0f);
      hout[prow * 256 + (((n >> 3) ^ (prow & 31)) * 8) + (n & 7)] = f2bf(v);
    }
  }
}

__device__ __forceinline__ void layer_256_256(const unsigned short* hin, unsigned short* hout,
                                              const unsigned short* __restrict__ Wp,
                                              const float* __restrict__ bias,
                                              int m0, int lane) {
  const int p = m0 + (lane & 15);
  const int quad = lane >> 4;
  f32x4 acc[16];
#pragma unroll
  for (int i = 0; i < 16; ++i) acc[i] = (f32x4){0.f, 0.f, 0.f, 0.f};
  for (int kt = 0; kt < 8; ++kt) {
    bf16x8 a = *reinterpret_cast<const bf16x8*>(hin + p * 256 + (((kt * 4 + quad) ^ (p & 31)) * 8));
#pragma unroll
    for (int nt = 0; nt < 16; ++nt) {
      bf16x8 b = *reinterpret_cast<const bf16x8*>(Wp + ((kt * 16 + nt) * 64 + lane) * 8);
      acc[nt] = __builtin_amdgcn_mfma_f32_16x16x32_bf16(a, b, acc[nt], 0, 0, 0);
    }
  }
  epilogue_relu_store(hout, acc, bias, m0, lane);
}

// ---------------------------------------------------------------- density MLP
// 64 points/WG. L1 (K=3) fp32 VALU; L2 (256x256) + L3 (256x16) bf16 MFMA.
// out16[P][0] = sigma (trunc_exp), [1..15] = geo.
__global__ __launch_bounds__(256, 2)
void k_density(const float* __restrict__ rays_o, const float* __restrict__ rays_d,
               const float* __restrict__ z,
               const float* __restrict__ W1, const float* __restrict__ b1,
               const unsigned short* __restrict__ Wp2, const float* __restrict__ b2,
               const unsigned short* __restrict__ Wp3, const float* __restrict__ b3,
               float* __restrict__ out16) {
  __shared__ unsigned short bufA[64 * 256];
  __shared__ unsigned short bufB[64 * 256];
  const int t = threadIdx.x;
  const int lane = t & 63;
  const int wid = t >> 6;
  const int P0 = blockIdx.x * 64;

  { // L1: h1 = relu(x @ W1 + b1)  (fp32, positions stay full precision)
    int p = t >> 2, sub = t & 3;
    int P = P0 + p, r = P >> 7;
    float zz = z[P];
    float x0 = rays_o[r * 3] + rays_d[r * 3] * zz;
    float x1 = rays_o[r * 3 + 1] + rays_d[r * 3 + 1] * zz;
    float x2 = rays_o[r * 3 + 2] + rays_d[r * 3 + 2] * zz;
    const f32x4* W1v = reinterpret_cast<const f32x4*>(W1);
    const f32x4* b1v = reinterpret_cast<const f32x4*>(b1);
    for (int it = 0; it < 8; ++it) {
      int gi = sub * 8 + it;
      f32x4 wa0 = W1v[gi * 2], wa1 = W1v[gi * 2 + 1];
      f32x4 wb0 = W1v[64 + gi * 2], wb1 = W1v[64 + gi * 2 + 1];
      f32x4 wc0 = W1v[128 + gi * 2], wc1 = W1v[128 + gi * 2 + 1];
      f32x4 bb0 = b1v[gi * 2], bb1 = b1v[gi * 2 + 1];
      u16x8 pk;
#pragma unroll
      for (int jj = 0; jj < 8; ++jj) {
        float wa = (jj < 4) ? wa0[jj & 3] : wa1[jj & 3];
        float wb = (jj < 4) ? wb0[jj & 3] : wb1[jj & 3];
        float wc = (jj < 4) ? wc0[jj & 3] : wc1[jj & 3];
        float bb = (jj < 4) ? bb0[jj & 3] : bb1[jj & 3];
        float h = x0 * wa + x1 * wb + x2 * wc + bb;
        pk[jj] = f2bf(fmaxf(h, 0.0f));
      }
      *reinterpret_cast<u16x8*>(&bufA[p * 256 + ((gi ^ (p & 31)) * 8)]) = pk;
    }
  }
  __syncthreads();
  layer_256_256(bufA, bufB, Wp2, b2, wid * 16, lane);
  __syncthreads();
  { // L3: 256 -> 16 (sigma + geo)
    int m0 = wid * 16;
    int p = m0 + (lane & 15);
    int quad = lane >> 4;
    f32x4 acc = {0.f, 0.f, 0.f, 0.f};
    for (int kt = 0; kt < 8; ++kt) {
      bf16x8 a = *reinterpret_cast<const bf16x8*>(&bufB[p * 256 + (((kt * 4 + quad) ^ (p & 31)) * 8)]);
      bf16x8 b = *reinterpret_cast<const bf16x8*>(&Wp3[(kt * 64 + lane) * 8]);
      acc = __builtin_amdgcn_mfma_f32_16x16x32_bf16(a, b, acc, 0, 0, 0);
    }
    int n = lane & 15;
    float bias = b3[n];
#pragma unroll
    for (int rr = 0; rr < 4; ++rr) {
      int prow = m0 + quad * 4 + rr;
      float v = acc[rr] + bias;
      if (n == 0) v = expf(fminf(fmaxf(v, -15.f), 15.f));  // trunc_exp
      out16[(size_t)(P0 + prow) * 16 + n] = v;
    }
  }
}

// ------------------------------------------------- coarse weights + sample_pdf
__global__ void k_pdf(const float* __restrict__ z_c, const float* __restrict__ out16_c,
                      float* __restrict__ z_f) {
  __shared__ float sz[128], sl[128], sw[128], scdf[128], szmid[128];
  int r = blockIdx.x, i = threadIdx.x;  // 128 threads
  float zi = z_c[r * NSTEP + i];
  sz[i] = zi;
  float sg = out16_c[(size_t)(r * NSTEP + i) * 16];
  __syncthreads();
  float aug = (i < 127) ? (sz[i + 1] - zi) : (sz[127] - sz[126]);
  float alpha = 1.0f - expf(-aug * sg);
  float term = 1.0f - alpha + 1e-15f;
  sl[i] = logf(term);
  __syncthreads();
  for (int off = 1; off < 128; off <<= 1) {  // inclusive scan of log-terms
    float y = (i >= off) ? sl[i - off] : 0.0f;
    __syncthreads();
    sl[i] += y;
    __syncthreads();
  }
  float excl = (i > 0) ? sl[i - 1] : 0.0f;
  float w = alpha * expf(excl);
  sw[i] = w;
  __syncthreads();
  float v = (i < 126) ? (sw[i + 1] + 1e-5f) : 0.0f;  // weights[:,1:-1] + 1e-5
  sl[i] = v;
  __syncthreads();
  for (int off = 1; off < 128; off <<= 1) {
    float y = (i >= off) ? sl[i - off] : 0.0f;
    __syncthreads();
    sl[i] += y;
    __syncthreads();
  }
  float total = sl[125];
  if (i <= 126) scdf[i] = (i == 0) ? 0.0f : sl[i - 1] / total;
  if (i < 127) szmid[i] = 0.5f * (sz[i] + sz[i + 1]);
  __syncthreads();
  const float lo = 0.5f / 128.0f, hi = 1.0f - 0.5f / 128.0f;
  float u = lo + (hi - lo) * ((float)i / 127.0f);
  int loI = 0, hiI = 127;  // searchsorted right over scdf[0..126]
  while (loI < hiI) {
    int mid = (loI + hiI) >> 1;
    if (scdf[mid] > u) hiI = mid; else loI = mid + 1;
  }
  int inds = loI;
  int below = inds - 1; if (below < 0) below = 0; if (below > 126) below = 126;
  int above = inds; if (above > 126) above = 126;
  float c0 = scdf[below], c1 = scdf[above];
  float b0 = szmid[below], b1 = szmid[above];
  float dn = c1 - c0; if (dn < 1e-5f) dn = 1.0f;
  float tt = (u - c0) / dn;
  z_f[r * NSTEP + i] = b0 + tt * (b1 - b0);
}

// ---------------------------------------------- merge (stable) + final weights
__global__ void k_merge(const float* __restrict__ z_c, const float* __restrict__ z_f,
                        const float* __restrict__ out16_c, const float* __restrict__ out16_f,
                        float* __restrict__ z_m, int* __restrict__ order,
                        float* __restrict__ wgt) {
  __shared__ float szc[128], szf[128], szm[256], sl[256];
  __shared__ int sord[256];
  int r = blockIdx.x, t = threadIdx.x;  // 256 threads
  if (t < 128) szc[t] = z_c[r * NSTEP + t];
  else szf[t - 128] = z_f[r * NSTEP + t - 128];
  __syncthreads();
  int pos; float myz;
  if (t < 128) {  // coarse i: pos = i + #{zf < zc[i]}   (ties: coarse first)
    myz = szc[t];
    int lo = 0, hi = 128;
    while (lo < hi) { int m = (lo + hi) >> 1; if (szf[m] < myz) lo = m + 1; else hi = m; }
    pos = t + lo;
  } else {        // fine j: pos = j + #{zc <= zf[j]}
    int j = t - 128; myz = szf[j];
    int lo = 0, hi = 128;
    while (lo < hi) { int m = (lo + hi) >> 1; if (szc[m] <= myz) lo = m + 1; else hi = m; }
    pos = j + lo;
  }
  szm[pos] = myz; sord[pos] = t;
  __syncthreads();
  z_m[r * TSAMP + t] = szm[t];
  order[r * TSAMP + t] = sord[t];
  int src = sord[t];
  float sg = (src < 128) ? out16_c[(size_t)(r * NSTEP + src) * 16]
                         : out16_f[(size_t)(r * NSTEP + src - 128) * 16];
  float zt = szm[t];
  float aug = (t < 255) ? (szm[t + 1] - zt) : (szm[255] - szm[254]);
  float alpha = 1.0f - expf(-aug * sg);
  sl[t] = logf(1.0f - alpha + 1e-15f);
  __syncthreads();
  for (int off = 1; off < 256; off <<= 1) {
    float y = (t >= off) ? sl[t - off] : 0.0f;
    __syncthreads();
    sl[t] += y;
    __syncthreads();
  }
  float excl = (t > 0) ? sl[t - 1] : 0.0f;
  wgt[r * TSAMP + t] = alpha * expf(excl);
}

// ---------------------------------------------------------------- color MLP
__global__ __launch_bounds__(256, 2)
void k_color(const float* __restrict__ rays_d, const int* __restrict__ order,
             const float* __restrict__ wgt,
             const float* __restrict__ out16_c, const float* __restrict__ out16_f,
             const unsigned short* __restrict__ Wp1, const float* __restrict__ cb1,
             const unsigned short* __restrict__ Wp2, const float* __restrict__ cb2,
             const unsigned short* __restrict__ Wp3, const float* __restrict__ cb3,
             float* __restrict__ rgb) {
  __shared__ unsigned short bufA[64 * 256];
  __shared__ unsigned short bufB[64 * 256];
  const int t = threadIdx.x;
  const int lane = t & 63;
  const int wid = t >> 6;
  const int P0 = blockIdx.x * 64;
  int anypred;
  { // build X = [dir(3), geo(15), pad] as bf16 in bufB (stride 32, XOR swizzle by p&3)
    int p = t >> 2, sub = t & 3;
    int P = P0 + p, r = P >> 8;
    float w = wgt[P];
    int src = order[P];
    const float* g16 = (src < 128) ? (out16_c + (size_t)(r * NSTEP + src) * 16)
                                   : (out16_f + (size_t)(r * NSTEP + src - 128) * 16);
    u16x8 pk;
#pragma unroll
    for (int jj = 0; jj < 8; ++jj) {
      int c = sub * 8 + jj;
      float v = 0.0f;
      if (c < 3) v = rays_d[r * 3 + c];
      else if (c < 18) v = g16[c - 2];  // geo[c-3] = out16[1 + c-3]
      pk[jj] = f2bf(v);
    }
    *reinterpret_cast<u16x8*>(&bufB[p * 32 + ((sub ^ (p & 3)) * 8)]) = pk;
    anypred = (sub == 0) && (w > 1e-4f);
  }
  if (!__syncthreads_or(anypred)) return;  // whole tile masked: rgb never read
  { // L1: K=32 (padded 18) MFMA
    int m0 = wid * 16;
    int p = m0 + (lane & 15);
    int quad = lane >> 4;
    bf16x8 a = *reinterpret_cast<const bf16x8*>(&bufB[p * 32 + ((quad ^ (p & 3)) * 8)]);
    f32x4 acc[16];
#pragma unroll
    for (int i = 0; i < 16; ++i) acc[i] = (f32x4){0.f, 0.f, 0.f, 0.f};
#pragma unroll
    for (int nt = 0; nt < 16; ++nt) {
      bf16x8 b = *reinterpret_cast<const bf16x8*>(&Wp1[(nt * 64 + lane) * 8]);
      acc[nt] = __builtin_amdgcn_mfma_f32_16x16x32_bf16(a, b, acc[nt], 0, 0, 0);
    }
    epilogue_relu_store(bufA, acc, cb1, m0, lane);
  }
  __syncthreads();
  layer_256_256(bufA, bufB, Wp2, cb2, wid * 16, lane);
  __syncthreads();
  { // L3: 256 -> 3 (padded 16), sigmoid
    int m0 = wid * 16;
    int p = m0 + (lane & 15);
    int quad = lane >> 4;
    f32x4 acc = {0.f, 0.f, 0.f, 0.f};
    for (int kt = 0; kt < 8; ++kt) {
      bf16x8 a = *reinterpret_cast<const bf16x8*>(&bufB[p * 256 + (((kt * 4 + quad) ^ (p & 31)) * 8)]);
      bf16x8 b = *reinterpret_cast<const bf16x8*>(&Wp3[(kt * 64 + lane) * 8]);
      acc = __builtin_amdgcn_mfma_f32_16x16x32_bf16(a, b, acc, 0, 0, 0);
    }
    int n = lane & 15;
    if (n < 3) {
      float bias = cb3[n];
#pragma unroll
      for (int rr = 0; rr < 4; ++rr) {
        int prow = m0 + quad * 4 + rr;
        float v = acc[rr] + bias;
        rgb[(size_t)(P0 + prow) * 3 + n] = 1.0f / (1.0f + expf(-v));
      }
    }
  }
}

// ------------------------------------------------------- final per-ray outputs
__device__ __forceinline__ float block_reduce(float v, float* s, int t) {
  s[t] = v;
  __syncthreads();
  for (int off = 128; off > 0; off >>= 1) {
    if (t < off) s[t] += s[t + off];
    __syncthreads();
  }
  float r = s[0];
  __syncthreads();
  return r;
}

__global__ void k_final(const float* __restrict__ z_m, const float* __restrict__ wgt,
                        const float* __restrict__ rgb, float* __restrict__ out) {
  __shared__ float sz[256], sw[256], smid[256], sred[256];
  int r = blockIdx.x, t = threadIdx.x;  // 256 threads
  float zt = z_m[r * TSAMP + t];
  float wt = wgt[r * TSAMP + t];
  sz[t] = zt; sw[t] = wt;
  __syncthreads();
  float znext = (t < 255) ? sz[t + 1] : (1.0f / 128.0f);  // sample_dist
  smid[t] = 0.5f * zt + 0.5f * znext;
  float cr = 0.f, cg = 0.f, cb = 0.f;
  if (wt > 1e-4f) {
    size_t base = (size_t)(r * TSAMP + t) * 3;
    cr = rgb[base]; cg = rgb[base + 1]; cb = rgb[base + 2];
  }
  __syncthreads();
  float mt = smid[t];
  float acc = 0.f;
  for (int j = 0; j < 256; ++j) acc += fabsf(mt - smid[j]) * sw[j];
  acc *= wt;
  float wsum = block_reduce(wt, sred, t);
  float depth = block_reduce(wt * zt, sred, t);
  float ir = block_reduce(wt * cr, sred, t);
  float ig = block_reduce(wt * cg, sred, t);
  float ib = block_reduce(wt * cb, sred, t);
  float S = block_reduce(acc, sred, t);
  if (t == 0) {
    const float bgc = 206.0f / 255.0f;
    float loss = S / (depth + 1e-6f);
    if (loss < 1e-3f) loss = 0.0f;
    out[r * 5 + 0] = ir + (1.0f - wsum) * bgc;
    out[r * 5 + 1] = ig + (1.0f - wsum) * bgc;
    out[r * 5 + 2] = ib + (1.0f - wsum) * bgc;
    out[r * 5 + 3] = depth;
    out[r * 5 + 4] = loss;
  }
}

// ---------------------------------------------------------------- launch
extern "C" void kernel_launch(void* const* d_in, const int* in_sizes, int n_in,
                              void* d_out, int out_size, void* d_ws, size_t ws_size,
                              hipStream_t stream) {
  const float* rays_o = (const float*)d_in[0];
  const float* rays_d = (const float*)d_in[1];
  const float* dW1 = (const float*)d_in[2];
  const float* db1 = (const float*)d_in[3];
  const float* dW2 = (const float*)d_in[4];
  const float* db2 = (const float*)d_in[5];
  const float* dW3 = (const float*)d_in[6];
  const float* db3 = (const float*)d_in[7];
  const float* cW1 = (const float*)d_in[8];
  const float* cb1 = (const float*)d_in[9];
  const float* cW2 = (const float*)d_in[10];
  const float* cb2 = (const float*)d_in[11];
  const float* cW3 = (const float*)d_in[12];
  const float* cb3 = (const float*)d_in[13];
  // num_steps / upsample_steps fixed at 128/128 (compile-time).

  char* ws = (char*)d_ws;
  size_t off = 0;
  auto alloc = [&](size_t bytes) -> void* {
    void* p = ws + off;
    off += (bytes + 255) & ~(size_t)255;
    return p;
  };
  unsigned short* Wp_d2 = (unsigned short*)alloc(65536 * 2);
  unsigned short* Wp_d3 = (unsigned short*)alloc(4096 * 2);
  unsigned short* Wp_c1 = (unsigned short*)alloc(8192 * 2);
  unsigned short* Wp_c2 = (unsigned short*)alloc(65536 * 2);
  unsigned short* Wp_c3 = (unsigned short*)alloc(4096 * 2);
  float* z_c  = (float*)alloc((size_t)NRAYS * NSTEP * 4);
  float* z_f  = (float*)alloc((size_t)NRAYS * NSTEP * 4);
  float* o16c = (float*)alloc((size_t)NRAYS * NSTEP * 16 * 4);
  float* o16f = (float*)alloc((size_t)NRAYS * NSTEP * 16 * 4);
  float* z_m  = (float*)alloc((size_t)NRAYS * TSAMP * 4);
  int*   ordr = (int*)alloc((size_t)NRAYS * TSAMP * 4);
  float* wgt  = (float*)alloc((size_t)NRAYS * TSAMP * 4);
  float* rgb  = (float*)alloc((size_t)NRAYS * TSAMP * 3 * 4);
  (void)ws_size; (void)in_sizes; (void)n_in; (void)out_size;

  k_pack<<<65536 / 256, 256, 0, stream>>>(dW2, Wp_d2, 256, 256, 16, 65536);
  k_pack<<<4096 / 256, 256, 0, stream>>>(dW3, Wp_d3, 256, 16, 1, 4096);
  k_pack<<<8192 / 256, 256, 0, stream>>>(cW1, Wp_c1, 18, 256, 16, 8192);
  k_pack<<<65536 / 256, 256, 0, stream>>>(cW2, Wp_c2, 256, 256, 16, 65536);
  k_pack<<<4096 / 256, 256, 0, stream>>>(cW3, Wp_c3, 256, 3, 1, 4096);

  k_raysetup<<<NRAYS, 128, 0, stream>>>(rays_o, rays_d, z_c);
  k_density<<<(NRAYS * NSTEP) / 64, 256, 0, stream>>>(
      rays_o, rays_d, z_c, dW1, db1, Wp_d2, db2, Wp_d3, db3, o16c);
  k_pdf<<<NRAYS, 128, 0, stream>>>(z_c, o16c, z_f);
  k_density<<<(NRAYS * NSTEP) / 64, 256, 0, stream>>>(
      rays_o, rays_d, z_f, dW1, db1, Wp_d2, db2, Wp_d3, db3, o16f);
  k_merge<<<NRAYS, 256, 0, stream>>>(z_c, z_f, o16c, o16f, z_m, ordr, wgt);
  k_color<<<(NRAYS * TSAMP) / 64, 256, 0, stream>>>(
      rays_d, ordr, wgt, o16c, o16f, Wp_c1, cb1, Wp_c2, cb2, Wp_c3, cb3, rgb);
  k_final<<<NRAYS, 256, 0, stream>>>(z_m, wgt, rgb, (float*)d_out);
}

// Round 2
// 568.298 us; speedup vs baseline: 1.2624x; 1.2624x over previous
//
#include <hip/hip_runtime.h>

// NeRF renderer pipeline for MI355X (gfx950).
// R2: N-split MFMA layers — each wave owns a 64-col slice of the 256-wide
// layers and loops all 4 m-tiles, cutting per-wave B (weight) L2 traffic 4x.
// R1 counters showed k_color MfmaUtil=14%, VALUBusy=33%, HBM=1.4% -> B-refetch
// from L2 (1 MB/CU/layer-pass) was the limiter.

typedef float f32x4 __attribute__((ext_vector_type(4)));
typedef __bf16 bf16x8 __attribute__((ext_vector_type(8)));
typedef unsigned short u16x8 __attribute__((ext_vector_type(8)));

#define NRAYS 2048
#define NSTEP 128
#define TSAMP 256
#define MIN_NEAR 0.05f

__device__ __forceinline__ unsigned short f2bf(float f) {
  unsigned int u = __float_as_uint(f);
  u += 0x7FFFu + ((u >> 16) & 1u);   // round-to-nearest-even
  return (unsigned short)(u >> 16);
}

// ---------------------------------------------------------------- weight pack
// dst[((kt*NT+nt)*64+lane)*8+j] = W[k][n], k=kt*32+(lane>>4)*8+j, n=nt*16+(lane&15)
__global__ void k_pack(const float* __restrict__ W, unsigned short* __restrict__ dst,
                       int K, int Norig, int NT, int total) {
  int idx = blockIdx.x * 256 + threadIdx.x;
  if (idx >= total) return;
  int per = NT * 512;
  int kt = idx / per;
  int rm = idx % per;
  int nt = rm >> 9;
  int lane = (rm >> 3) & 63;
  int j = rm & 7;
  int k = kt * 32 + ((lane >> 4) << 3) + j;
  int n = nt * 16 + (lane & 15);
  float v = (k < K && n < Norig) ? W[k * Norig + n] : 0.0f;
  dst[idx] = f2bf(v);
}

// ---------------------------------------------------------------- ray setup
__global__ void k_raysetup(const float* __restrict__ o, const float* __restrict__ d,
                           float* __restrict__ z_c) {
  int r = blockIdx.x, i = threadIdx.x;  // 128 threads
  float ox = o[r * 3], oy = o[r * 3 + 1], oz = o[r * 3 + 2];
  float dx = d[r * 3], dy = d[r * 3 + 1], dz = d[r * 3 + 2];
  float b = ox * dx + oy * dy + oz * dz;
  float c = ox * ox + oy * oy + oz * oz - 1.0f;
  float disc = fmaxf(b * b - c, 0.0f);
  float zmax = fmaxf(-b + sqrtf(disc), MIN_NEAR + 1e-3f);
  float zmin = MIN_NEAR;
  float t = (float)i / 127.0f;
  float z = zmin + (zmax - zmin) * t;
  z = fminf(fmaxf(z, zmin), zmax);
  z_c[r * NSTEP + i] = z;
}

// ---------------------------------------------------------------- MFMA helpers
// LDS h layout: h[p][n] at u16 offset p*256 + ((n>>3)^(p&31))*8 + (n&7) (XOR swizzle)

// N-split 256x256 layer: wave `wid` computes cols [wid*64, wid*64+64) for all
// 64 points. B traffic/wave = 32 KB (vs 128 KB M-split).
__device__ __forceinline__ void layer_256_256_ns(const unsigned short* hin,
                                                 unsigned short* hout,
                                                 const unsigned short* __restrict__ Wp,
                                                 const float* __restrict__ bias,
                                                 int wid, int lane) {
  const int quad = lane >> 4;
  const int col = lane & 15;
  f32x4 acc[16];  // [mt][ntl]
#pragma unroll
  for (int i = 0; i < 16; ++i) acc[i] = (f32x4){0.f, 0.f, 0.f, 0.f};
#pragma unroll 2
  for (int kt = 0; kt < 8; ++kt) {
    bf16x8 a[4], b[4];
#pragma unroll
    for (int mt = 0; mt < 4; ++mt) {
      int p = mt * 16 + col;
      a[mt] = *reinterpret_cast<const bf16x8*>(hin + p * 256 + (((kt * 4 + quad) ^ (p & 31)) * 8));
    }
#pragma unroll
    for (int ntl = 0; ntl < 4; ++ntl)
      b[ntl] = *reinterpret_cast<const bf16x8*>(Wp + ((kt * 16 + wid * 4 + ntl) * 64 + lane) * 8);
#pragma unroll
    for (int mt = 0; mt < 4; ++mt)
#pragma unroll
      for (int ntl = 0; ntl < 4; ++ntl)
        acc[mt * 4 + ntl] = __builtin_amdgcn_mfma_f32_16x16x32_bf16(a[mt], b[ntl], acc[mt * 4 + ntl], 0, 0, 0);
  }
#pragma unroll
  for (int ntl = 0; ntl < 4; ++ntl) {
    int n = wid * 64 + ntl * 16 + col;
    float bv = bias[n];
#pragma unroll
    for (int mt = 0; mt < 4; ++mt)
#pragma unroll
      for (int rr = 0; rr < 4; ++rr) {
        int prow = mt * 16 + quad * 4 + rr;
        float v = fmaxf(acc[mt * 4 + ntl][rr] + bv, 0.0f);
        hout[prow * 256 + (((n >> 3) ^ (prow & 31)) * 8) + (n & 7)] = f2bf(v);
      }
  }
}

// ---------------------------------------------------------------- density MLP
// 64 points/WG. L1 (K=3) fp32 VALU; L2 N-split MFMA; L3 (256x16) M-split MFMA.
// out16[P][0] = sigma (trunc_exp), [1..15] = geo.
__global__ __launch_bounds__(256, 2)
void k_density(const float* __restrict__ rays_o, const float* __restrict__ rays_d,
               const float* __restrict__ z,
               const float* __restrict__ W1, const float* __restrict__ b1,
               const unsigned short* __restrict__ Wp2, const float* __restrict__ b2,
               const unsigned short* __restrict__ Wp3, const float* __restrict__ b3,
               float* __restrict__ out16) {
  __shared__ unsigned short bufA[64 * 256];
  __shared__ unsigned short bufB[64 * 256];
  const int t = threadIdx.x;
  const int lane = t & 63;
  const int wid = t >> 6;
  const int P0 = blockIdx.x * 64;

  { // L1: h1 = relu(x @ W1 + b1)  (fp32, positions stay full precision)
    int p = t >> 2, sub = t & 3;
    int P = P0 + p, r = P >> 7;
    float zz = z[P];
    float x0 = rays_o[r * 3] + rays_d[r * 3] * zz;
    float x1 = rays_o[r * 3 + 1] + rays_d[r * 3 + 1] * zz;
    float x2 = rays_o[r * 3 + 2] + rays_d[r * 3 + 2] * zz;
    const f32x4* W1v = reinterpret_cast<const f32x4*>(W1);
    const f32x4* b1v = reinterpret_cast<const f32x4*>(b1);
    for (int it = 0; it < 8; ++it) {
      int gi = sub * 8 + it;
      f32x4 wa0 = W1v[gi * 2], wa1 = W1v[gi * 2 + 1];
      f32x4 wb0 = W1v[64 + gi * 2], wb1 = W1v[64 + gi * 2 + 1];
      f32x4 wc0 = W1v[128 + gi * 2], wc1 = W1v[128 + gi * 2 + 1];
      f32x4 bb0 = b1v[gi * 2], bb1 = b1v[gi * 2 + 1];
      u16x8 pk;
#pragma unroll
      for (int jj = 0; jj < 8; ++jj) {
        float wa = (jj < 4) ? wa0[jj & 3] : wa1[jj & 3];
        float wb = (jj < 4) ? wb0[jj & 3] : wb1[jj & 3];
        float wc = (jj < 4) ? wc0[jj & 3] : wc1[jj & 3];
        float bb = (jj < 4) ? bb0[jj & 3] : bb1[jj & 3];
        float h = x0 * wa + x1 * wb + x2 * wc + bb;
        pk[jj] = f2bf(fmaxf(h, 0.0f));
      }
      *reinterpret_cast<u16x8*>(&bufA[p * 256 + ((gi ^ (p & 31)) * 8)]) = pk;
    }
  }
  __syncthreads();
  layer_256_256_ns(bufA, bufB, Wp2, b2, wid, lane);
  __syncthreads();
  { // L3: 256 -> 16 (sigma + geo), M-split (N too small to split)
    int m0 = wid * 16;
    int p = m0 + (lane & 15);
    int quad = lane >> 4;
    f32x4 acc = {0.f, 0.f, 0.f, 0.f};
    for (int kt = 0; kt < 8; ++kt) {
      bf16x8 a = *reinterpret_cast<const bf16x8*>(&bufB[p * 256 + (((kt * 4 + quad) ^ (p & 31)) * 8)]);
      bf16x8 b = *reinterpret_cast<const bf16x8*>(&Wp3[(kt * 64 + lane) * 8]);
      acc = __builtin_amdgcn_mfma_f32_16x16x32_bf16(a, b, acc, 0, 0, 0);
    }
    int n = lane & 15;
    float bias = b3[n];
#pragma unroll
    for (int rr = 0; rr < 4; ++rr) {
      int prow = m0 + quad * 4 + rr;
      float v = acc[rr] + bias;
      if (n == 0) v = expf(fminf(fmaxf(v, -15.f), 15.f));  // trunc_exp
      out16[(size_t)(P0 + prow) * 16 + n] = v;
    }
  }
}

// ------------------------------------------------- coarse weights + sample_pdf
__global__ void k_pdf(const float* __restrict__ z_c, const float* __restrict__ out16_c,
                      float* __restrict__ z_f) {
  __shared__ float sz[128], sl[128], sw[128], scdf[128], szmid[128];
  int r = blockIdx.x, i = threadIdx.x;  // 128 threads
  float zi = z_c[r * NSTEP + i];
  sz[i] = zi;
  float sg = out16_c[(size_t)(r * NSTEP + i) * 16];
  __syncthreads();
  float aug = (i < 127) ? (sz[i + 1] - zi) : (sz[127] - sz[126]);
  float alpha = 1.0f - expf(-aug * sg);
  float term = 1.0f - alpha + 1e-15f;
  sl[i] = logf(term);
  __syncthreads();
  for (int off = 1; off < 128; off <<= 1) {  // inclusive scan of log-terms
    float y = (i >= off) ? sl[i - off] : 0.0f;
    __syncthreads();
    sl[i] += y;
    __syncthreads();
  }
  float excl = (i > 0) ? sl[i - 1] : 0.0f;
  float w = alpha * expf(excl);
  sw[i] = w;
  __syncthreads();
  float v = (i < 126) ? (sw[i + 1] + 1e-5f) : 0.0f;  // weights[:,1:-1] + 1e-5
  sl[i] = v;
  __syncthreads();
  for (int off = 1; off < 128; off <<= 1) {
    float y = (i >= off) ? sl[i - off] : 0.0f;
    __syncthreads();
    sl[i] += y;
    __syncthreads();
  }
  float total = sl[125];
  if (i <= 126) scdf[i] = (i == 0) ? 0.0f : sl[i - 1] / total;
  if (i < 127) szmid[i] = 0.5f * (sz[i] + sz[i + 1]);
  __syncthreads();
  const float lo = 0.5f / 128.0f, hi = 1.0f - 0.5f / 128.0f;
  float u = lo + (hi - lo) * ((float)i / 127.0f);
  int loI = 0, hiI = 127;  // searchsorted right over scdf[0..126]
  while (loI < hiI) {
    int mid = (loI + hiI) >> 1;
    if (scdf[mid] > u) hiI = mid; else loI = mid + 1;
  }
  int inds = loI;
  int below = inds - 1; if (below < 0) below = 0; if (below > 126) below = 126;
  int above = inds; if (above > 126) above = 126;
  float c0 = scdf[below], c1 = scdf[above];
  float b0 = szmid[below], b1 = szmid[above];
  float dn = c1 - c0; if (dn < 1e-5f) dn = 1.0f;
  float tt = (u - c0) / dn;
  z_f[r * NSTEP + i] = b0 + tt * (b1 - b0);
}

// ---------------------------------------------- merge (stable) + final weights
__global__ void k_merge(const float* __restrict__ z_c, const float* __restrict__ z_f,
                        const float* __restrict__ out16_c, const float* __restrict__ out16_f,
                        float* __restrict__ z_m, int* __restrict__ order,
                        float* __restrict__ wgt) {
  __shared__ float szc[128], szf[128], szm[256], sl[256];
  __shared__ int sord[256];
  int r = blockIdx.x, t = threadIdx.x;  // 256 threads
  if (t < 128) szc[t] = z_c[r * NSTEP + t];
  else szf[t - 128] = z_f[r * NSTEP + t - 128];
  __syncthreads();
  int pos; float myz;
  if (t < 128) {  // coarse i: pos = i + #{zf < zc[i]}   (ties: coarse first)
    myz = szc[t];
    int lo = 0, hi = 128;
    while (lo < hi) { int m = (lo + hi) >> 1; if (szf[m] < myz) lo = m + 1; else hi = m; }
    pos = t + lo;
  } else {        // fine j: pos = j + #{zc <= zf[j]}
    int j = t - 128; myz = szf[j];
    int lo = 0, hi = 128;
    while (lo < hi) { int m = (lo + hi) >> 1; if (szc[m] <= myz) lo = m + 1; else hi = m; }
    pos = j + lo;
  }
  szm[pos] = myz; sord[pos] = t;
  __syncthreads();
  z_m[r * TSAMP + t] = szm[t];
  order[r * TSAMP + t] = sord[t];
  int src = sord[t];
  float sg = (src < 128) ? out16_c[(size_t)(r * NSTEP + src) * 16]
                         : out16_f[(size_t)(r * NSTEP + src - 128) * 16];
  float zt = szm[t];
  float aug = (t < 255) ? (szm[t + 1] - zt) : (szm[255] - szm[254]);
  float alpha = 1.0f - expf(-aug * sg);
  sl[t] = logf(1.0f - alpha + 1e-15f);
  __syncthreads();
  for (int off = 1; off < 256; off <<= 1) {
    float y = (t >= off) ? sl[t - off] : 0.0f;
    __syncthreads();
    sl[t] += y;
    __syncthreads();
  }
  float excl = (t > 0) ? sl[t - 1] : 0.0f;
  wgt[r * TSAMP + t] = alpha * expf(excl);
}

// ---------------------------------------------------------------- color MLP
__global__ __launch_bounds__(256, 2)
void k_color(const float* __restrict__ rays_d, const int* __restrict__ order,
             const float* __restrict__ wgt,
             const float* __restrict__ out16_c, const float* __restrict__ out16_f,
             const unsigned short* __restrict__ Wp1, const float* __restrict__ cb1,
             const unsigned short* __restrict__ Wp2, const float* __restrict__ cb2,
             const unsigned short* __restrict__ Wp3, const float* __restrict__ cb3,
             float* __restrict__ rgb) {
  __shared__ unsigned short bufA[64 * 256];
  __shared__ unsigned short bufB[64 * 256];
  const int t = threadIdx.x;
  const int lane = t & 63;
  const int wid = t >> 6;
  const int P0 = blockIdx.x * 64;
  int anypred;
  { // build X = [dir(3), geo(15), pad] as bf16 in bufB (stride 32, XOR swizzle by p&3)
    int p = t >> 2, sub = t & 3;
    int P = P0 + p, r = P >> 8;
    float w = wgt[P];
    int src = order[P];
    const float* g16 = (src < 128) ? (out16_c + (size_t)(r * NSTEP + src) * 16)
                                   : (out16_f + (size_t)(r * NSTEP + src - 128) * 16);
    u16x8 pk;
#pragma unroll
    for (int jj = 0; jj < 8; ++jj) {
      int c = sub * 8 + jj;
      float v = 0.0f;
      if (c < 3) v = rays_d[r * 3 + c];
      else if (c < 18) v = g16[c - 2];  // geo[c-3] = out16[1 + c-3]
      pk[jj] = f2bf(v);
    }
    *reinterpret_cast<u16x8*>(&bufB[p * 32 + ((sub ^ (p & 3)) * 8)]) = pk;
    anypred = (sub == 0) && (w > 1e-4f);
  }
  if (!__syncthreads_or(anypred)) return;  // whole tile masked: rgb never read
  { // L1: K=32 (padded 18), N-split: wave computes its 64 cols for all 4 m-tiles
    const int quad = lane >> 4;
    const int col = lane & 15;
    bf16x8 a[4], b[4];
#pragma unroll
    for (int mt = 0; mt < 4; ++mt) {
      int p = mt * 16 + col;
      a[mt] = *reinterpret_cast<const bf16x8*>(&bufB[p * 32 + ((quad ^ (p & 3)) * 8)]);
    }
#pragma unroll
    for (int ntl = 0; ntl < 4; ++ntl)
      b[ntl] = *reinterpret_cast<const bf16x8*>(&Wp1[((wid * 4 + ntl) * 64 + lane) * 8]);
    f32x4 acc[16];
#pragma unroll
    for (int i = 0; i < 16; ++i) acc[i] = (f32x4){0.f, 0.f, 0.f, 0.f};
#pragma unroll
    for (int mt = 0; mt < 4; ++mt)
#pragma unroll
      for (int ntl = 0; ntl < 4; ++ntl)
        acc[mt * 4 + ntl] = __builtin_amdgcn_mfma_f32_16x16x32_bf16(a[mt], b[ntl], acc[mt * 4 + ntl], 0, 0, 0);
#pragma unroll
    for (int ntl = 0; ntl < 4; ++ntl) {
      int n = wid * 64 + ntl * 16 + col;
      float bv = cb1[n];
#pragma unroll
      for (int mt = 0; mt < 4; ++mt)
#pragma unroll
        for (int rr = 0; rr < 4; ++rr) {
          int prow = mt * 16 + quad * 4 + rr;
          float v = fmaxf(acc[mt * 4 + ntl][rr] + bv, 0.0f);
          bufA[prow * 256 + (((n >> 3) ^ (prow & 31)) * 8) + (n & 7)] = f2bf(v);
        }
    }
  }
  __syncthreads();
  layer_256_256_ns(bufA, bufB, Wp2, cb2, wid, lane);
  __syncthreads();
  { // L3: 256 -> 3 (padded 16), sigmoid, M-split
    int m0 = wid * 16;
    int p = m0 + (lane & 15);
    int quad = lane >> 4;
    f32x4 acc = {0.f, 0.f, 0.f, 0.f};
    for (int kt = 0; kt < 8; ++kt) {
      bf16x8 a = *reinterpret_cast<const bf16x8*>(&bufB[p * 256 + (((kt * 4 + quad) ^ (p & 31)) * 8)]);
      bf16x8 b = *reinterpret_cast<const bf16x8*>(&Wp3[(kt * 64 + lane) * 8]);
      acc = __builtin_amdgcn_mfma_f32_16x16x32_bf16(a, b, acc, 0, 0, 0);
    }
    int n = lane & 15;
    if (n < 3) {
      float bias = cb3[n];
#pragma unroll
      for (int rr = 0; rr < 4; ++rr) {
        int prow = m0 + quad * 4 + rr;
        float v = acc[rr] + bias;
        rgb[(size_t)(P0 + prow) * 3 + n] = 1.0f / (1.0f + expf(-v));
      }
    }
  }
}

// ------------------------------------------------------- final per-ray outputs
__device__ __forceinline__ float block_reduce(float v, float* s, int t) {
  s[t] = v;
  __syncthreads();
  for (int off = 128; off > 0; off >>= 1) {
    if (t < off) s[t] += s[t + off];
    __syncthreads();
  }
  float r = s[0];
  __syncthreads();
  return r;
}

__global__ void k_final(const float* __restrict__ z_m, const float* __restrict__ wgt,
                        const float* __restrict__ rgb, float* __restrict__ out) {
  __shared__ float sz[256], sw[256], smid[256], sred[256];
  int r = blockIdx.x, t = threadIdx.x;  // 256 threads
  float zt = z_m[r * TSAMP + t];
  float wt = wgt[r * TSAMP + t];
  sz[t] = zt; sw[t] = wt;
  __syncthreads();
  float znext = (t < 255) ? sz[t + 1] : (1.0f / 128.0f);  // sample_dist
  smid[t] = 0.5f * zt + 0.5f * znext;
  float cr = 0.f, cg = 0.f, cb = 0.f;
  if (wt > 1e-4f) {
    size_t base = (size_t)(r * TSAMP + t) * 3;
    cr = rgb[base]; cg = rgb[base + 1]; cb = rgb[base + 2];
  }
  __syncthreads();
  float mt = smid[t];
  float acc = 0.f;
  for (int j = 0; j < 256; ++j) acc += fabsf(mt - smid[j]) * sw[j];
  acc *= wt;
  float wsum = block_reduce(wt, sred, t);
  float depth = block_reduce(wt * zt, sred, t);
  float ir = block_reduce(wt * cr, sred, t);
  float ig = block_reduce(wt * cg, sred, t);
  float ib = block_reduce(wt * cb, sred, t);
  float S = block_reduce(acc, sred, t);
  if (t == 0) {
    const float bgc = 206.0f / 255.0f;
    float loss = S / (depth + 1e-6f);
    if (loss < 1e-3f) loss = 0.0f;
    out[r * 5 + 0] = ir + (1.0f - wsum) * bgc;
    out[r * 5 + 1] = ig + (1.0f - wsum) * bgc;
    out[r * 5 + 2] = ib + (1.0f - wsum) * bgc;
    out[r * 5 + 3] = depth;
    out[r * 5 + 4] = loss;
  }
}

// ---------------------------------------------------------------- launch
extern "C" void kernel_launch(void* const* d_in, const int* in_sizes, int n_in,
                              void* d_out, int out_size, void* d_ws, size_t ws_size,
                              hipStream_t stream) {
  const float* rays_o = (const float*)d_in[0];
  const float* rays_d = (const float*)d_in[1];
  const float* dW1 = (const float*)d_in[2];
  const float* db1 = (const float*)d_in[3];
  const float* dW2 = (const float*)d_in[4];
  const float* db2 = (const float*)d_in[5];
  const float* dW3 = (const float*)d_in[6];
  const float* db3 = (const float*)d_in[7];
  const float* cW1 = (const float*)d_in[8];
  const float* cb1 = (const float*)d_in[9];
  const float* cW2 = (const float*)d_in[10];
  const float* cb2 = (const float*)d_in[11];
  const float* cW3 = (const float*)d_in[12];
  const float* cb3 = (const float*)d_in[13];
  // num_steps / upsample_steps fixed at 128/128 (compile-time).

  char* ws = (char*)d_ws;
  size_t off = 0;
  auto alloc = [&](size_t bytes) -> void* {
    void* p = ws + off;
    off += (bytes + 255) & ~(size_t)255;
    return p;
  };
  unsigned short* Wp_d2 = (unsigned short*)alloc(65536 * 2);
  unsigned short* Wp_d3 = (unsigned short*)alloc(4096 * 2);
  unsigned short* Wp_c1 = (unsigned short*)alloc(8192 * 2);
  unsigned short* Wp_c2 = (unsigned short*)alloc(65536 * 2);
  unsigned short* Wp_c3 = (unsigned short*)alloc(4096 * 2);
  float* z_c  = (float*)alloc((size_t)NRAYS * NSTEP * 4);
  float* z_f  = (float*)alloc((size_t)NRAYS * NSTEP * 4);
  float* o16c = (float*)alloc((size_t)NRAYS * NSTEP * 16 * 4);
  float* o16f = (float*)alloc((size_t)NRAYS * NSTEP * 16 * 4);
  float* z_m  = (float*)alloc((size_t)NRAYS * TSAMP * 4);
  int*   ordr = (int*)alloc((size_t)NRAYS * TSAMP * 4);
  float* wgt  = (float*)alloc((size_t)NRAYS * TSAMP * 4);
  float* rgb  = (float*)alloc((size_t)NRAYS * TSAMP * 3 * 4);
  (void)ws_size; (void)in_sizes; (void)n_in; (void)out_size;

  k_pack<<<65536 / 256, 256, 0, stream>>>(dW2, Wp_d2, 256, 256, 16, 65536);
  k_pack<<<4096 / 256, 256, 0, stream>>>(dW3, Wp_d3, 256, 16, 1, 4096);
  k_pack<<<8192 / 256, 256, 0, stream>>>(cW1, Wp_c1, 18, 256, 16, 8192);
  k_pack<<<65536 / 256, 256, 0, stream>>>(cW2, Wp_c2, 256, 256, 16, 65536);
  k_pack<<<4096 / 256, 256, 0, stream>>>(cW3, Wp_c3, 256, 3, 1, 4096);

  k_raysetup<<<NRAYS, 128, 0, stream>>>(rays_o, rays_d, z_c);
  k_density<<<(NRAYS * NSTEP) / 64, 256, 0, stream>>>(
      rays_o, rays_d, z_c, dW1, db1, Wp_d2, db2, Wp_d3, db3, o16c);
  k_pdf<<<NRAYS, 128, 0, stream>>>(z_c, o16c, z_f);
  k_density<<<(NRAYS * NSTEP) / 64, 256, 0, stream>>>(
      rays_o, rays_d, z_f, dW1, db1, Wp_d2, db2, Wp_d3, db3, o16f);
  k_merge<<<NRAYS, 256, 0, stream>>>(z_c, z_f, o16c, o16f, z_m, ordr, wgt);
  k_color<<<(NRAYS * TSAMP) / 64, 256, 0, stream>>>(
      rays_d, ordr, wgt, o16c, o16f, Wp_c1, cb1, Wp_c2, cb2, Wp_c3, cb3, rgb);
  k_final<<<NRAYS, 256, 0, stream>>>(z_m, wgt, rgb, (float*)d_out);
}

// Round 3
// 493.229 us; speedup vs baseline: 1.4545x; 1.1522x over previous
//
#include <hip/hip_runtime.h>

// NeRF renderer pipeline for MI355X (gfx950).
// R3: (1) single 32KB LDS activation buffer + deferred in-place epilogue ->
// 4 WG/CU (was 2); (2) operand-swapped MFMA (A=weights, B=acts) so the
// epilogue is ds_write_b64 (4 consecutive features per lane) and L3 outputs
// are global_store_dwordx4. R2 showed k_density Mfma 9% / VALU 25% / occ 23%
// with no pipe saturated -> latency-bound at 2 WG/CU.

typedef float f32x4 __attribute__((ext_vector_type(4)));
typedef __bf16 bf16x8 __attribute__((ext_vector_type(8)));
typedef unsigned short u16x8 __attribute__((ext_vector_type(8)));
typedef unsigned short u16x4 __attribute__((ext_vector_type(4)));

#define NRAYS 2048
#define NSTEP 128
#define TSAMP 256
#define MIN_NEAR 0.05f

__device__ __forceinline__ unsigned short f2bf(float f) {
  unsigned int u = __float_as_uint(f);
  u += 0x7FFFu + ((u >> 16) & 1u);   // round-to-nearest-even
  return (unsigned short)(u >> 16);
}

// ---------------------------------------------------------------- weight pack
// dst[((kt*NT+nt)*64+lane)*8+j] = W[k][n], k=kt*32+(lane>>4)*8+j, n=nt*16+(lane&15)
// Serves as A-operand frag of the swapped layer: A[m=n][k] = W[k][n].
__global__ void k_pack(const float* __restrict__ W, unsigned short* __restrict__ dst,
                       int K, int Norig, int NT, int total) {
  int idx = blockIdx.x * 256 + threadIdx.x;
  if (idx >= total) return;
  int per = NT * 512;
  int kt = idx / per;
  int rm = idx % per;
  int nt = rm >> 9;
  int lane = (rm >> 3) & 63;
  int j = rm & 7;
  int k = kt * 32 + ((lane >> 4) << 3) + j;
  int n = nt * 16 + (lane & 15);
  float v = (k < K && n < Norig) ? W[k * Norig + n] : 0.0f;
  dst[idx] = f2bf(v);
}

// ---------------------------------------------------------------- ray setup
__global__ void k_raysetup(const float* __restrict__ o, const float* __restrict__ d,
                           float* __restrict__ z_c) {
  int r = blockIdx.x, i = threadIdx.x;  // 128 threads
  float ox = o[r * 3], oy = o[r * 3 + 1], oz = o[r * 3 + 2];
  float dx = d[r * 3], dy = d[r * 3 + 1], dz = d[r * 3 + 2];
  float b = ox * dx + oy * dy + oz * dz;
  float c = ox * ox + oy * oy + oz * oz - 1.0f;
  float disc = fmaxf(b * b - c, 0.0f);
  float zmax = fmaxf(-b + sqrtf(disc), MIN_NEAR + 1e-3f);
  float zmin = MIN_NEAR;
  float t = (float)i / 127.0f;
  float z = zmin + (zmax - zmin) * t;
  z = fminf(fmaxf(z, zmin), zmax);
  z_c[r * NSTEP + i] = z;
}

// ---------------------------------------------------------------- MFMA helpers
// LDS act layout: h[p][n] at u16 offset p*256 + ((n>>3)^(p&31))*8 + (n&7)

// Swapped-operand N-split 256x256 layer, IN-PLACE on buf.
// Wave `wid` computes features [wid*64, wid*64+64) for all 64 points.
// Reads all of buf into acc, barrier, writes back over buf (b64 stores),
// barrier before next consumer.
__device__ __forceinline__ void layer_256_256_swap(unsigned short* buf,
                                                   const unsigned short* __restrict__ Wp,
                                                   const float* __restrict__ bias,
                                                   int wid, int lane) {
  const int quad = lane >> 4;
  const int col = lane & 15;
  f32x4 acc[16];  // [ntl][pt]
#pragma unroll
  for (int i = 0; i < 16; ++i) acc[i] = (f32x4){0.f, 0.f, 0.f, 0.f};
#pragma unroll 2
  for (int kt = 0; kt < 8; ++kt) {
    bf16x8 w[4], x[4];
#pragma unroll
    for (int ntl = 0; ntl < 4; ++ntl)
      w[ntl] = *reinterpret_cast<const bf16x8*>(Wp + ((kt * 16 + wid * 4 + ntl) * 64 + lane) * 8);
#pragma unroll
    for (int pt = 0; pt < 4; ++pt) {
      int p = pt * 16 + col;
      x[pt] = *reinterpret_cast<const bf16x8*>(buf + p * 256 + (((kt * 4 + quad) ^ (p & 31)) * 8));
    }
#pragma unroll
    for (int ntl = 0; ntl < 4; ++ntl)
#pragma unroll
      for (int pt = 0; pt < 4; ++pt)
        acc[ntl * 4 + pt] = __builtin_amdgcn_mfma_f32_16x16x32_bf16(w[ntl], x[pt], acc[ntl * 4 + pt], 0, 0, 0);
  }
  __syncthreads();  // all reads done before in-place overwrite
#pragma unroll
  for (int ntl = 0; ntl < 4; ++ntl) {
    int n = wid * 64 + ntl * 16 + quad * 4;  // 4 consecutive features per lane
    f32x4 bv = *reinterpret_cast<const f32x4*>(bias + n);
#pragma unroll
    for (int pt = 0; pt < 4; ++pt) {
      int p = pt * 16 + col;
      u16x4 pk;
#pragma unroll
      for (int rr = 0; rr < 4; ++rr)
        pk[rr] = f2bf(fmaxf(acc[ntl * 4 + pt][rr] + bv[rr], 0.0f));
      *reinterpret_cast<u16x4*>(buf + p * 256 + (((n >> 3) ^ (p & 31)) * 8) + (n & 7)) = pk;
    }
  }
  __syncthreads();
}

// ---------------------------------------------------------------- density MLP
// 64 points/WG, 4 WG/CU. L1 (K=3) fp32 VALU; L2 swapped N-split MFMA in-place;
// L3 (256x16) swapped MFMA -> dwordx4 global store.
__global__ __launch_bounds__(256, 4)
void k_density(const float* __restrict__ rays_o, const float* __restrict__ rays_d,
               const float* __restrict__ z,
               const float* __restrict__ W1, const float* __restrict__ b1,
               const unsigned short* __restrict__ Wp2, const float* __restrict__ b2,
               const unsigned short* __restrict__ Wp3, const float* __restrict__ b3,
               float* __restrict__ out16) {
  __shared__ unsigned short buf[64 * 256];
  const int t = threadIdx.x;
  const int lane = t & 63;
  const int wid = t >> 6;
  const int P0 = blockIdx.x * 64;

  { // L1: h1 = relu(x @ W1 + b1)  (fp32, positions stay full precision)
    int p = t >> 2, sub = t & 3;
    int P = P0 + p, r = P >> 7;
    float zz = z[P];
    float x0 = rays_o[r * 3] + rays_d[r * 3] * zz;
    float x1 = rays_o[r * 3 + 1] + rays_d[r * 3 + 1] * zz;
    float x2 = rays_o[r * 3 + 2] + rays_d[r * 3 + 2] * zz;
    const f32x4* W1v = reinterpret_cast<const f32x4*>(W1);
    const f32x4* b1v = reinterpret_cast<const f32x4*>(b1);
    for (int it = 0; it < 8; ++it) {
      int gi = sub * 8 + it;
      f32x4 wa0 = W1v[gi * 2], wa1 = W1v[gi * 2 + 1];
      f32x4 wb0 = W1v[64 + gi * 2], wb1 = W1v[64 + gi * 2 + 1];
      f32x4 wc0 = W1v[128 + gi * 2], wc1 = W1v[128 + gi * 2 + 1];
      f32x4 bb0 = b1v[gi * 2], bb1 = b1v[gi * 2 + 1];
      u16x8 pk;
#pragma unroll
      for (int jj = 0; jj < 8; ++jj) {
        float wa = (jj < 4) ? wa0[jj & 3] : wa1[jj & 3];
        float wb = (jj < 4) ? wb0[jj & 3] : wb1[jj & 3];
        float wc = (jj < 4) ? wc0[jj & 3] : wc1[jj & 3];
        float bb = (jj < 4) ? bb0[jj & 3] : bb1[jj & 3];
        float h = x0 * wa + x1 * wb + x2 * wc + bb;
        pk[jj] = f2bf(fmaxf(h, 0.0f));
      }
      *reinterpret_cast<u16x8*>(&buf[p * 256 + ((gi ^ (p & 31)) * 8)]) = pk;
    }
  }
  __syncthreads();
  layer_256_256_swap(buf, Wp2, b2, wid, lane);
  { // L3: 256 -> 16 (sigma + geo); wave wid owns p-tile wid
    const int quad = lane >> 4;
    const int col = lane & 15;
    const int p = wid * 16 + col;
    f32x4 acc = {0.f, 0.f, 0.f, 0.f};
#pragma unroll 2
    for (int kt = 0; kt < 8; ++kt) {
      bf16x8 w = *reinterpret_cast<const bf16x8*>(&Wp3[(kt * 64 + lane) * 8]);
      bf16x8 x = *reinterpret_cast<const bf16x8*>(&buf[p * 256 + (((kt * 4 + quad) ^ (p & 31)) * 8)]);
      acc = __builtin_amdgcn_mfma_f32_16x16x32_bf16(w, x, acc, 0, 0, 0);
    }
    int n0 = quad * 4;  // lane holds features n0..n0+3 of point p
    f32x4 bv = *reinterpret_cast<const f32x4*>(b3 + n0);
    f32x4 v;
#pragma unroll
    for (int rr = 0; rr < 4; ++rr) v[rr] = acc[rr] + bv[rr];
    if (quad == 0) v[0] = expf(fminf(fmaxf(v[0], -15.f), 15.f));  // trunc_exp
    *reinterpret_cast<f32x4*>(out16 + (size_t)(P0 + p) * 16 + n0) = v;
  }
}

// ------------------------------------------------- coarse weights + sample_pdf
__global__ void k_pdf(const float* __restrict__ z_c, const float* __restrict__ out16_c,
                      float* __restrict__ z_f) {
  __shared__ float sz[128], sl[128], sw[128], scdf[128], szmid[128];
  int r = blockIdx.x, i = threadIdx.x;  // 128 threads
  float zi = z_c[r * NSTEP + i];
  sz[i] = zi;
  float sg = out16_c[(size_t)(r * NSTEP + i) * 16];
  __syncthreads();
  float aug = (i < 127) ? (sz[i + 1] - zi) : (sz[127] - sz[126]);
  float alpha = 1.0f - expf(-aug * sg);
  float term = 1.0f - alpha + 1e-15f;
  sl[i] = logf(term);
  __syncthreads();
  for (int off = 1; off < 128; off <<= 1) {  // inclusive scan of log-terms
    float y = (i >= off) ? sl[i - off] : 0.0f;
    __syncthreads();
    sl[i] += y;
    __syncthreads();
  }
  float excl = (i > 0) ? sl[i - 1] : 0.0f;
  float w = alpha * expf(excl);
  sw[i] = w;
  __syncthreads();
  float v = (i < 126) ? (sw[i + 1] + 1e-5f) : 0.0f;  // weights[:,1:-1] + 1e-5
  sl[i] = v;
  __syncthreads();
  for (int off = 1; off < 128; off <<= 1) {
    float y = (i >= off) ? sl[i - off] : 0.0f;
    __syncthreads();
    sl[i] += y;
    __syncthreads();
  }
  float total = sl[125];
  if (i <= 126) scdf[i] = (i == 0) ? 0.0f : sl[i - 1] / total;
  if (i < 127) szmid[i] = 0.5f * (sz[i] + sz[i + 1]);
  __syncthreads();
  const float lo = 0.5f / 128.0f, hi = 1.0f - 0.5f / 128.0f;
  float u = lo + (hi - lo) * ((float)i / 127.0f);
  int loI = 0, hiI = 127;  // searchsorted right over scdf[0..126]
  while (loI < hiI) {
    int mid = (loI + hiI) >> 1;
    if (scdf[mid] > u) hiI = mid; else loI = mid + 1;
  }
  int inds = loI;
  int below = inds - 1; if (below < 0) below = 0; if (below > 126) below = 126;
  int above = inds; if (above > 126) above = 126;
  float c0 = scdf[below], c1 = scdf[above];
  float b0 = szmid[below], b1 = szmid[above];
  float dn = c1 - c0; if (dn < 1e-5f) dn = 1.0f;
  float tt = (u - c0) / dn;
  z_f[r * NSTEP + i] = b0 + tt * (b1 - b0);
}

// ---------------------------------------------- merge (stable) + final weights
__global__ void k_merge(const float* __restrict__ z_c, const float* __restrict__ z_f,
                        const float* __restrict__ out16_c, const float* __restrict__ out16_f,
                        float* __restrict__ z_m, int* __restrict__ order,
                        float* __restrict__ wgt) {
  __shared__ float szc[128], szf[128], szm[256], sl[256];
  __shared__ int sord[256];
  int r = blockIdx.x, t = threadIdx.x;  // 256 threads
  if (t < 128) szc[t] = z_c[r * NSTEP + t];
  else szf[t - 128] = z_f[r * NSTEP + t - 128];
  __syncthreads();
  int pos; float myz;
  if (t < 128) {  // coarse i: pos = i + #{zf < zc[i]}   (ties: coarse first)
    myz = szc[t];
    int lo = 0, hi = 128;
    while (lo < hi) { int m = (lo + hi) >> 1; if (szf[m] < myz) lo = m + 1; else hi = m; }
    pos = t + lo;
  } else {        // fine j: pos = j + #{zc <= zf[j]}
    int j = t - 128; myz = szf[j];
    int lo = 0, hi = 128;
    while (lo < hi) { int m = (lo + hi) >> 1; if (szc[m] <= myz) lo = m + 1; else hi = m; }
    pos = j + lo;
  }
  szm[pos] = myz; sord[pos] = t;
  __syncthreads();
  z_m[r * TSAMP + t] = szm[t];
  order[r * TSAMP + t] = sord[t];
  int src = sord[t];
  float sg = (src < 128) ? out16_c[(size_t)(r * NSTEP + src) * 16]
                         : out16_f[(size_t)(r * NSTEP + src - 128) * 16];
  float zt = szm[t];
  float aug = (t < 255) ? (szm[t + 1] - zt) : (szm[255] - szm[254]);
  float alpha = 1.0f - expf(-aug * sg);
  sl[t] = logf(1.0f - alpha + 1e-15f);
  __syncthreads();
  for (int off = 1; off < 256; off <<= 1) {
    float y = (t >= off) ? sl[t - off] : 0.0f;
    __syncthreads();
    sl[t] += y;
    __syncthreads();
  }
  float excl = (t > 0) ? sl[t - 1] : 0.0f;
  wgt[r * TSAMP + t] = alpha * expf(excl);
}

// ---------------------------------------------------------------- color MLP
__global__ __launch_bounds__(256, 4)
void k_color(const float* __restrict__ rays_d, const int* __restrict__ order,
             const float* __restrict__ wgt,
             const float* __restrict__ out16_c, const float* __restrict__ out16_f,
             const unsigned short* __restrict__ Wp1, const float* __restrict__ cb1,
             const unsigned short* __restrict__ Wp2, const float* __restrict__ cb2,
             const unsigned short* __restrict__ Wp3, const float* __restrict__ cb3,
             float* __restrict__ rgb4) {
  __shared__ unsigned short buf[64 * 256];
  __shared__ unsigned short xbuf[64 * 32];
  const int t = threadIdx.x;
  const int lane = t & 63;
  const int wid = t >> 6;
  const int P0 = blockIdx.x * 64;
  int anypred;
  { // build X = [dir(3), geo(15), pad] as bf16 in xbuf (stride 32, XOR swizzle)
    int p = t >> 2, sub = t & 3;
    int P = P0 + p, r = P >> 8;
    float w = wgt[P];
    int src = order[P];
    const float* g16 = (src < 128) ? (out16_c + (size_t)(r * NSTEP + src) * 16)
                                   : (out16_f + (size_t)(r * NSTEP + src - 128) * 16);
    u16x8 pk;
#pragma unroll
    for (int jj = 0; jj < 8; ++jj) {
      int c = sub * 8 + jj;
      float v = 0.0f;
      if (c < 3) v = rays_d[r * 3 + c];
      else if (c < 18) v = g16[c - 2];  // geo[c-3] = out16[1 + c-3]
      pk[jj] = f2bf(v);
    }
    *reinterpret_cast<u16x8*>(&xbuf[p * 32 + ((sub ^ (p & 3)) * 8)]) = pk;
    anypred = (sub == 0) && (w > 1e-4f);
  }
  if (!__syncthreads_or(anypred)) return;  // whole tile masked: rgb never read
  { // L1: K=32 (padded 18), swapped N-split; write h1 into buf
    const int quad = lane >> 4;
    const int col = lane & 15;
    bf16x8 w[4], x[4];
#pragma unroll
    for (int ntl = 0; ntl < 4; ++ntl)
      w[ntl] = *reinterpret_cast<const bf16x8*>(&Wp1[((wid * 4 + ntl) * 64 + lane) * 8]);
#pragma unroll
    for (int pt = 0; pt < 4; ++pt) {
      int p = pt * 16 + col;
      x[pt] = *reinterpret_cast<const bf16x8*>(&xbuf[p * 32 + ((quad ^ (p & 3)) * 8)]);
    }
    f32x4 acc[16];
#pragma unroll
    for (int i = 0; i < 16; ++i) acc[i] = (f32x4){0.f, 0.f, 0.f, 0.f};
#pragma unroll
    for (int ntl = 0; ntl < 4; ++ntl)
#pragma unroll
      for (int pt = 0; pt < 4; ++pt)
        acc[ntl * 4 + pt] = __builtin_amdgcn_mfma_f32_16x16x32_bf16(w[ntl], x[pt], acc[ntl * 4 + pt], 0, 0, 0);
#pragma unroll
    for (int ntl = 0; ntl < 4; ++ntl) {
      int n = wid * 64 + ntl * 16 + quad * 4;
      f32x4 bv = *reinterpret_cast<const f32x4*>(cb1 + n);
#pragma unroll
      for (int pt = 0; pt < 4; ++pt) {
        int p = pt * 16 + col;
        u16x4 pk;
#pragma unroll
        for (int rr = 0; rr < 4; ++rr)
          pk[rr] = f2bf(fmaxf(acc[ntl * 4 + pt][rr] + bv[rr], 0.0f));
        *reinterpret_cast<u16x4*>(&buf[p * 256 + (((n >> 3) ^ (p & 31)) * 8) + (n & 7)]) = pk;
      }
    }
  }
  __syncthreads();
  layer_256_256_swap(buf, Wp2, cb2, wid, lane);
  { // L3: 256 -> 3 (padded 16), sigmoid; wave wid owns p-tile wid
    const int quad = lane >> 4;
    const int col = lane & 15;
    const int p = wid * 16 + col;
    f32x4 acc = {0.f, 0.f, 0.f, 0.f};
#pragma unroll 2
    for (int kt = 0; kt < 8; ++kt) {
      bf16x8 w = *reinterpret_cast<const bf16x8*>(&Wp3[(kt * 64 + lane) * 8]);
      bf16x8 x = *reinterpret_cast<const bf16x8*>(&buf[p * 256 + (((kt * 4 + quad) ^ (p & 31)) * 8)]);
      acc = __builtin_amdgcn_mfma_f32_16x16x32_bf16(w, x, acc, 0, 0, 0);
    }
    if (quad == 0) {  // lane holds rows 0..3 = r,g,b,junk of point p
      f32x4 v;
#pragma unroll
      for (int rr = 0; rr < 3; ++rr) {
        float s = acc[rr] + cb3[rr];
        v[rr] = 1.0f / (1.0f + expf(-s));
      }
      v[3] = 0.0f;
      *reinterpret_cast<f32x4*>(rgb4 + (size_t)(P0 + p) * 4) = v;
    }
  }
}

// ------------------------------------------------------- final per-ray outputs
__device__ __forceinline__ float block_reduce(float v, float* s, int t) {
  s[t] = v;
  __syncthreads();
  for (int off = 128; off > 0; off >>= 1) {
    if (t < off) s[t] += s[t + off];
    __syncthreads();
  }
  float r = s[0];
  __syncthreads();
  return r;
}

__global__ void k_final(const float* __restrict__ z_m, const float* __restrict__ wgt,
                        const float* __restrict__ rgb4, float* __restrict__ out) {
  __shared__ float sz[256], sw[256], smid[256], sred[256];
  int r = blockIdx.x, t = threadIdx.x;  // 256 threads
  float zt = z_m[r * TSAMP + t];
  float wt = wgt[r * TSAMP + t];
  sz[t] = zt; sw[t] = wt;
  __syncthreads();
  float znext = (t < 255) ? sz[t + 1] : (1.0f / 128.0f);  // sample_dist
  smid[t] = 0.5f * zt + 0.5f * znext;
  float cr = 0.f, cg = 0.f, cb = 0.f;
  if (wt > 1e-4f) {
    f32x4 c = *reinterpret_cast<const f32x4*>(rgb4 + (size_t)(r * TSAMP + t) * 4);
    cr = c[0]; cg = c[1]; cb = c[2];
  }
  __syncthreads();
  float mt = smid[t];
  float acc = 0.f;
  for (int j = 0; j < 256; ++j) acc += fabsf(mt - smid[j]) * sw[j];
  acc *= wt;
  float wsum = block_reduce(wt, sred, t);
  float depth = block_reduce(wt * zt, sred, t);
  float ir = block_reduce(wt * cr, sred, t);
  float ig = block_reduce(wt * cg, sred, t);
  float ib = block_reduce(wt * cb, sred, t);
  float S = block_reduce(acc, sred, t);
  if (t == 0) {
    const float bgc = 206.0f / 255.0f;
    float loss = S / (depth + 1e-6f);
    if (loss < 1e-3f) loss = 0.0f;
    out[r * 5 + 0] = ir + (1.0f - wsum) * bgc;
    out[r * 5 + 1] = ig + (1.0f - wsum) * bgc;
    out[r * 5 + 2] = ib + (1.0f - wsum) * bgc;
    out[r * 5 + 3] = depth;
    out[r * 5 + 4] = loss;
  }
}

// ---------------------------------------------------------------- launch
extern "C" void kernel_launch(void* const* d_in, const int* in_sizes, int n_in,
                              void* d_out, int out_size, void* d_ws, size_t ws_size,
                              hipStream_t stream) {
  const float* rays_o = (const float*)d_in[0];
  const float* rays_d = (const float*)d_in[1];
  const float* dW1 = (const float*)d_in[2];
  const float* db1 = (const float*)d_in[3];
  const float* dW2 = (const float*)d_in[4];
  const float* db2 = (const float*)d_in[5];
  const float* dW3 = (const float*)d_in[6];
  const float* db3 = (const float*)d_in[7];
  const float* cW1 = (const float*)d_in[8];
  const float* cb1 = (const float*)d_in[9];
  const float* cW2 = (const float*)d_in[10];
  const float* cb2 = (const float*)d_in[11];
  const float* cW3 = (const float*)d_in[12];
  const float* cb3 = (const float*)d_in[13];
  // num_steps / upsample_steps fixed at 128/128 (compile-time).

  char* ws = (char*)d_ws;
  size_t off = 0;
  auto alloc = [&](size_t bytes) -> void* {
    void* p = ws + off;
    off += (bytes + 255) & ~(size_t)255;
    return p;
  };
  unsigned short* Wp_d2 = (unsigned short*)alloc(65536 * 2);
  unsigned short* Wp_d3 = (unsigned short*)alloc(4096 * 2);
  unsigned short* Wp_c1 = (unsigned short*)alloc(8192 * 2);
  unsigned short* Wp_c2 = (unsigned short*)alloc(65536 * 2);
  unsigned short* Wp_c3 = (unsigned short*)alloc(4096 * 2);
  float* z_c  = (float*)alloc((size_t)NRAYS * NSTEP * 4);
  float* z_f  = (float*)alloc((size_t)NRAYS * NSTEP * 4);
  float* o16c = (float*)alloc((size_t)NRAYS * NSTEP * 16 * 4);
  float* o16f = (float*)alloc((size_t)NRAYS * NSTEP * 16 * 4);
  float* z_m  = (float*)alloc((size_t)NRAYS * TSAMP * 4);
  int*   ordr = (int*)alloc((size_t)NRAYS * TSAMP * 4);
  float* wgt  = (float*)alloc((size_t)NRAYS * TSAMP * 4);
  float* rgb4 = (float*)alloc((size_t)NRAYS * TSAMP * 4 * 4);
  (void)ws_size; (void)in_sizes; (void)n_in; (void)out_size;

  k_pack<<<65536 / 256, 256, 0, stream>>>(dW2, Wp_d2, 256, 256, 16, 65536);
  k_pack<<<4096 / 256, 256, 0, stream>>>(dW3, Wp_d3, 256, 16, 1, 4096);
  k_pack<<<8192 / 256, 256, 0, stream>>>(cW1, Wp_c1, 18, 256, 16, 8192);
  k_pack<<<65536 / 256, 256, 0, stream>>>(cW2, Wp_c2, 256, 256, 16, 65536);
  k_pack<<<4096 / 256, 256, 0, stream>>>(cW3, Wp_c3, 256, 3, 1, 4096);

  k_raysetup<<<NRAYS, 128, 0, stream>>>(rays_o, rays_d, z_c);
  k_density<<<(NRAYS * NSTEP) / 64, 256, 0, stream>>>(
      rays_o, rays_d, z_c, dW1, db1, Wp_d2, db2, Wp_d3, db3, o16c);
  k_pdf<<<NRAYS, 128, 0, stream>>>(z_c, o16c, z_f);
  k_density<<<(NRAYS * NSTEP) / 64, 256, 0, stream>>>(
      rays_o, rays_d, z_f, dW1, db1, Wp_d2, db2, Wp_d3, db3, o16f);
  k_merge<<<NRAYS, 256, 0, stream>>>(z_c, z_f, o16c, o16f, z_m, ordr, wgt);
  k_color<<<(NRAYS * TSAMP) / 64, 256, 0, stream>>>(
      rays_d, ordr, wgt, o16c, o16f, Wp_c1, cb1, Wp_c2, cb2, Wp_c3, cb3, rgb4);
  k_final<<<NRAYS, 256, 0, stream>>>(z_m, wgt, rgb4, (float*)d_out);
}